// Round 5
// baseline (321.634 us; speedup 1.0000x reference)
//
#include <hip/hip_runtime.h>
#include <hip/hip_bf16.h>

typedef __bf16 bf16_t;
typedef __bf16 bf16x8 __attribute__((ext_vector_type(8)));
typedef __bf16 bf16x4 __attribute__((ext_vector_type(4)));
typedef float  f32x4  __attribute__((ext_vector_type(4)));

#define NB  8
#define NC  256
#define NC8 32
#define NN  4096
#define XS  264   // xs row stride in proj_fused (528B = 33*16, b128-aligned)

#define MFMA16(a, b, c) __builtin_amdgcn_mfma_f32_16x16x32_bf16((a), (b), (c), 0, 0, 0)

// ---------------------------------------------------------------------------
// Kernel 0: fp32 -> bf16 for all three weight matrices in one launch.
// ---------------------------------------------------------------------------
__global__ __launch_bounds__(256) void cvt_all(const float* __restrict__ wq,
                                               const float* __restrict__ wk,
                                               const float* __restrict__ wv,
                                               bf16_t* __restrict__ wqb,
                                               bf16_t* __restrict__ wkb,
                                               bf16_t* __restrict__ wvb) {
    int i = blockIdx.x * 256 + threadIdx.x;   // 0..20479
    const float* src; bf16_t* dst; int off;
    if (i < 2048)      { src = wq; dst = wqb; off = i; }
    else if (i < 4096) { src = wk; dst = wkb; off = i - 2048; }
    else               { src = wv; dst = wvb; off = i - 4096; }
    float4 v = reinterpret_cast<const float4*>(src)[off];
    bf16x4 o;
    o[0] = (bf16_t)v.x; o[1] = (bf16_t)v.y; o[2] = (bf16_t)v.z; o[3] = (bf16_t)v.w;
    reinterpret_cast<bf16x4*>(dst)[off] = o;
}

// ---------------------------------------------------------------------------
// Kernel 1: FUSED transpose + q/k/v projections per (b, n-tile of 64).
// (unchanged: hoisted x loads + weight prefetch)
// ---------------------------------------------------------------------------
__global__ __launch_bounds__(256) void proj_fused(const float* __restrict__ x,
                                                  const bf16_t* __restrict__ wq,
                                                  const float* __restrict__ bq,
                                                  const bf16_t* __restrict__ wk,
                                                  const float* __restrict__ bk,
                                                  const bf16_t* __restrict__ wv,
                                                  const float* __restrict__ bv,
                                                  bf16_t* __restrict__ ft,
                                                  bf16_t* __restrict__ gt,
                                                  bf16_t* __restrict__ h) {
    __shared__ bf16_t tile[64][72];
    __shared__ bf16_t xs[64 * XS];      // [n_loc][c]

    const int bx = blockIdx.x;          // 512
    const int b  = bx >> 6;
    const int n0 = (bx & 63) * 64;
    const int t  = threadIdx.x;
    const int w    = t >> 6;
    const int lane = t & 63;
    const int q    = lane >> 4;
    const int r    = lane & 15;

    const int cl  = t >> 4;
    const int nl  = (t & 15) * 4;
    const int nb_ = t >> 3;
    const int cl2 = (t & 7) * 8;

    // ---- hoisted x loads: all 16 in flight at once
    float4 xv[16];
#pragma unroll
    for (int cp = 0; cp < 4; ++cp)
#pragma unroll
        for (int p = 0; p < 4; ++p)
            xv[4 * cp + p] = *reinterpret_cast<const float4*>(
                x + ((size_t)b * NC + 64 * cp + cl + 16 * p) * NN + n0 + nl);

    for (int cp = 0; cp < 4; ++cp) {
#pragma unroll
        for (int p = 0; p < 4; ++p) {
            const int cc = cl + 16 * p;
            float4 v = xv[4 * cp + p];
            bf16x4 bv4;
            bv4[0] = (bf16_t)v.x; bv4[1] = (bf16_t)v.y; bv4[2] = (bf16_t)v.z; bv4[3] = (bf16_t)v.w;
            *reinterpret_cast<bf16x4*>(&tile[cc][nl]) = bv4;
        }
        __syncthreads();
#pragma unroll
        for (int p = 0; p < 2; ++p) {
            const int nn = nb_ + 32 * p;
            bf16x8 v;
            for (int i = 0; i < 8; ++i) v[i] = tile[cl2 + i][nn];
            *reinterpret_cast<bf16x8*>(&xs[nn * XS + 64 * cp + cl2]) = v;
        }
        __syncthreads();
    }

    // ---- q/k projections (weight + activation prefetch, depth 1)
    {
        const bf16_t* xrow = &xs[(16 * w + r) * XS];
        f32x4 accq[2], acck[2];
        for (int ot = 0; ot < 2; ++ot) {
            accq[ot] = (f32x4){0.f, 0.f, 0.f, 0.f};
            acck[ot] = (f32x4){0.f, 0.f, 0.f, 0.f};
        }
        bf16x8 a_c  = *reinterpret_cast<const bf16x8*>(xrow + 8 * q);
        bf16x8 fq_c[2], fk_c[2];
#pragma unroll
        for (int ot = 0; ot < 2; ++ot) {
            fq_c[ot] = *reinterpret_cast<const bf16x8*>(wq + (size_t)(16 * ot + r) * NC + 8 * q);
            fk_c[ot] = *reinterpret_cast<const bf16x8*>(wk + (size_t)(16 * ot + r) * NC + 8 * q);
        }
        for (int k0 = 0; k0 < NC; k0 += 32) {
            const int kn = (k0 + 32 < NC) ? k0 + 32 : 0;
            bf16x8 a_n = *reinterpret_cast<const bf16x8*>(xrow + kn + 8 * q);
            bf16x8 fq_n[2], fk_n[2];
#pragma unroll
            for (int ot = 0; ot < 2; ++ot) {
                fq_n[ot] = *reinterpret_cast<const bf16x8*>(wq + (size_t)(16 * ot + r) * NC + kn + 8 * q);
                fk_n[ot] = *reinterpret_cast<const bf16x8*>(wk + (size_t)(16 * ot + r) * NC + kn + 8 * q);
            }
#pragma unroll
            for (int ot = 0; ot < 2; ++ot) {
                accq[ot] = MFMA16(a_c, fq_c[ot], accq[ot]);
                acck[ot] = MFMA16(a_c, fk_c[ot], acck[ot]);
            }
            a_c = a_n;
#pragma unroll
            for (int ot = 0; ot < 2; ++ot) { fq_c[ot] = fq_n[ot]; fk_c[ot] = fk_n[ot]; }
        }
        for (int ot = 0; ot < 2; ++ot) {
            const int o = 16 * ot + r;
            const float biq = bq[o];
            const float bik = bk[o];
            for (int i = 0; i < 4; ++i) {
                const int n = n0 + 16 * w + 4 * q + i;
                ft[((size_t)b * NN + n) * NC8 + o] = (bf16_t)(accq[ot][i] + biq);
                gt[((size_t)b * NN + n) * NC8 + o] = (bf16_t)(acck[ot][i] + bik);
            }
        }
    }

    // ---- v projection (wv prefetch, depth 1)
    f32x4 vacc[4][4];
    for (int ct = 0; ct < 4; ++ct)
        for (int nt = 0; nt < 4; ++nt) vacc[ct][nt] = (f32x4){0.f, 0.f, 0.f, 0.f};

    bf16x8 wv_c[4];
#pragma unroll
    for (int ct = 0; ct < 4; ++ct)
        wv_c[ct] = *reinterpret_cast<const bf16x8*>(
            wv + (size_t)(64 * ct + 16 * w + r) * NC + 8 * q);

    for (int k0 = 0; k0 < NC; k0 += 32) {
        const int kn = (k0 + 32 < NC) ? k0 + 32 : 0;
        bf16x8 wv_n[4];
#pragma unroll
        for (int ct = 0; ct < 4; ++ct)
            wv_n[ct] = *reinterpret_cast<const bf16x8*>(
                wv + (size_t)(64 * ct + 16 * w + r) * NC + kn + 8 * q);
        bf16x8 bfr[4];
#pragma unroll
        for (int nt = 0; nt < 4; ++nt)
            bfr[nt] = *reinterpret_cast<const bf16x8*>(&xs[(16 * nt + r) * XS + k0 + 8 * q]);
#pragma unroll
        for (int ct = 0; ct < 4; ++ct)
#pragma unroll
            for (int nt = 0; nt < 4; ++nt)
                vacc[ct][nt] = MFMA16(wv_c[ct], bfr[nt], vacc[ct][nt]);
#pragma unroll
        for (int ct = 0; ct < 4; ++ct) wv_c[ct] = wv_n[ct];
    }
    for (int ct = 0; ct < 4; ++ct) {
        for (int nt = 0; nt < 4; ++nt) {
            for (int i = 0; i < 4; ++i) {
                const int c = 64 * ct + 16 * w + 4 * q + i;
                const int n = n0 + 16 * nt + r;
                h[((size_t)b * NC + c) * NN + n] = (bf16_t)(vacc[ct][nt][i] + bv[c]);
            }
        }
    }
}

// ---------------------------------------------------------------------------
// Kernel 2: attention, 4 waves (R0 base) with ROTATED schedule:
//   S(ii+1) and exp/P-write(ii+1) are interleaved INTO the O phase of iter ii
//   (S0 after O-step0, exp0 after O-step1, S1 after O-step2, exp1 after
//   O-step3), writing to the OTHER P buffer. The post-barrier critical chain
//   is reduced to the pf ds_read latency only; exp/S issue hides under the
//   O-MFMA pipe. One non-draining barrier per iteration (lgkmcnt only, no
//   vmcnt drain -> af/h prefetch survives). af loads are a full iteration
//   ahead (afA) / ~2 O-steps ahead (afB). lm gates l for the rotated tail.
//   Buffer safety: iter ii reads P[ii&1], writes P[(ii+1)&1]; all readers of
//   the write target finished before the barrier at the top of iter ii.
// ---------------------------------------------------------------------------
#define O_STEP(HU, HL, KC, LOFF)                                               \
    {                                                                          \
        _Pragma("unroll")                                                      \
        for (int ct = 0; ct < 4; ++ct)                                         \
            HL[ct] = *reinterpret_cast<const bf16x8*>(hrow[ct] + (LOFF));      \
        bf16x8 pf[4];                                                          \
        _Pragma("unroll")                                                      \
        for (int mt = 0; mt < 4; ++mt) {                                       \
            const int row = 16 * mt + r;                                       \
            pf[mt] = *reinterpret_cast<const bf16x8*>(                         \
                &Pb[(row << 7) + (((4 * (KC) + q) ^ rq) << 3)]);               \
        }                                                                      \
        _Pragma("unroll")                                                      \
        for (int ct = 0; ct < 4; ++ct)                                         \
            _Pragma("unroll")                                                  \
            for (int mt = 0; mt < 4; ++mt)                                     \
                acc[ct][mt] = MFMA16(HU[ct], pf[mt], acc[ct][mt]);             \
    }

#define S_STEP(SS, AF)                                                         \
    {                                                                          \
        _Pragma("unroll")                                                      \
        for (int mt = 0; mt < 4; ++mt) SS[mt] = MFMA16((AF), qf[mt], zero);    \
    }

#define EXPW(SS, T2, LMV)                                                      \
    {                                                                          \
        _Pragma("unroll")                                                      \
        for (int mt = 0; mt < 4; ++mt) {                                       \
            float e0 = __expf(SS[mt][0]);                                      \
            float e1 = __expf(SS[mt][1]);                                      \
            float e2 = __expf(SS[mt][2]);                                      \
            float e3 = __expf(SS[mt][3]);                                      \
            lp[mt] += (LMV) * ((e0 + e1) + (e2 + e3));                         \
            bf16x4 pv;                                                         \
            pv[0] = (bf16_t)e0; pv[1] = (bf16_t)e1;                            \
            pv[2] = (bf16_t)e2; pv[3] = (bf16_t)e3;                            \
            const int row  = 16 * mt + r;                                      \
            const int nblk = 4 * w + 2 * (T2) + (q >> 1);                      \
            *reinterpret_cast<bf16x4*>(                                        \
                &Pw[(row << 7) + ((nblk ^ rq) << 3) + 4 * (q & 1)]) = pv;      \
        }                                                                      \
    }

__global__ __launch_bounds__(256, 3) void attn(const bf16_t* __restrict__ ft,
                                               const bf16_t* __restrict__ gt,
                                               const bf16_t* __restrict__ h,
                                               float* __restrict__ out) {
    __shared__ bf16_t P[2 * 64 * 128];   // 32 KB, double buffered
    __shared__ float  l_lds[64];

    const int bx = blockIdx.x;       // 512
    const int b  = bx & 7;           // XCD pin
    const int m0 = (bx >> 3) * 64;
    const int tid  = threadIdx.x;
    const int w    = tid >> 6;       // 0..3
    const int lane = tid & 63;
    const int q    = lane >> 4;
    const int r    = lane & 15;
    const int rq   = r & 7;

    if (tid < 64) l_lds[tid] = 0.f;

    bf16x8 qf[4];
#pragma unroll
    for (int mt = 0; mt < 4; ++mt)
        qf[mt] = *reinterpret_cast<const bf16x8*>(
            gt + ((size_t)b * NN + m0 + 16 * mt + r) * NC8 + 8 * q);

    f32x4 acc[4][4];
#pragma unroll
    for (int ct = 0; ct < 4; ++ct)
#pragma unroll
        for (int mt = 0; mt < 4; ++mt) acc[ct][mt] = (f32x4){0.f, 0.f, 0.f, 0.f};
    float lp[4] = {0.f, 0.f, 0.f, 0.f};

    const bf16_t* fb = ft + (size_t)b * NN * NC8;
    const bf16_t* hb = h + (size_t)b * NC * NN;
    const f32x4 zero = (f32x4){0.f, 0.f, 0.f, 0.f};

    const bf16_t* hrow[4];
#pragma unroll
    for (int ct = 0; ct < 4; ++ct)
        hrow[ct] = hb + (size_t)(64 * w + 16 * ct + r) * NN + 8 * q;
    // f fragment base for wave rows [32w, 32w+32): row = 32w + 16*t2 + r
    const bf16_t* fptr = fb + (size_t)(32 * w + r) * NC8 + 8 * q;

    // ---- prologue: S(0) + exp(0) + write P[0]; h(kc0 of chunk 0); afA=f(1)
    f32x4 s0[4], s1[4];
    {
        bf16_t* Pw = P;
        bf16x8 a00 = *reinterpret_cast<const bf16x8*>(fptr);
        bf16x8 a01 = *reinterpret_cast<const bf16x8*>(fptr + (size_t)16 * NC8);
        S_STEP(s0, a00);
        S_STEP(s1, a01);
        EXPW(s0, 0, 1.f);
        EXPW(s1, 1, 1.f);
    }
    bf16x8 h0[4], h1[4];
#pragma unroll
    for (int ct = 0; ct < 4; ++ct)
        h0[ct] = *reinterpret_cast<const bf16x8*>(hrow[ct]);
    bf16x8 afA = *reinterpret_cast<const bf16x8*>(fptr + (size_t)128 * NC8);

    for (int ii = 0; ii < 32; ++ii) {
        const bf16_t* Pb = &P[(ii & 1) << 13];        // read chunk ii
        bf16_t* Pw = &P[((ii + 1) & 1) << 13];        // write chunk ii+1
        const int nb   = ii * 128;
        const int nld  = (ii + 1 < 32 ? ii + 1 : 31) * 128;   // chunk ii+1 (clamped)
        const int nld2 = (ii + 2 < 32 ? ii + 2 : 31) * 128;   // chunk ii+2 (clamped)
        const int nbn  = (ii + 1 < 32 ? nb + 128 : nb);
        const float lm = (ii + 1 < 32) ? 1.f : 0.f;

        // ---- non-draining barrier: P[ii&1] writes (prev iter) now visible
        asm volatile("s_waitcnt lgkmcnt(0)" ::: "memory");
        __builtin_amdgcn_sched_barrier(0);
        __builtin_amdgcn_s_barrier();
        __builtin_amdgcn_sched_barrier(0);

        __builtin_amdgcn_s_setprio(1);
        O_STEP(h0, h1, 0, nb + 32);
        S_STEP(s0, afA);                                      // S(ii+1, t2=0)
        bf16x8 afB = *reinterpret_cast<const bf16x8*>(fptr + (size_t)(nld + 16) * NC8);
        O_STEP(h1, h0, 1, nb + 64);
        EXPW(s0, 0, lm);                                      // exp(ii+1, t2=0) -> Pw
        O_STEP(h0, h1, 2, nb + 96);
        S_STEP(s1, afB);                                      // S(ii+1, t2=1)
        afA = *reinterpret_cast<const bf16x8*>(fptr + (size_t)nld2 * NC8);
        O_STEP(h1, h0, 3, nbn);
        EXPW(s1, 1, lm);                                      // exp(ii+1, t2=1) -> Pw
        __builtin_amdgcn_s_setprio(0);
    }

    // ---- reduce l partials (cold path)
    __syncthreads();
#pragma unroll
    for (int mt = 0; mt < 4; ++mt) {
        float v = lp[mt];
        v += __shfl_xor(v, 16);
        v += __shfl_xor(v, 32);
        if (q == 0) atomicAdd(&l_lds[16 * mt + r], v);
    }
    __syncthreads();

    // ---- epilogue: out[b][c][m] = acc / l[m]
#pragma unroll
    for (int ct = 0; ct < 4; ++ct) {
#pragma unroll
        for (int mt = 0; mt < 4; ++mt) {
            const int m = m0 + 16 * mt + r;
            const float linv = 1.0f / l_lds[16 * mt + r];
#pragma unroll
            for (int i = 0; i < 4; ++i) {
                const int c = 64 * w + 16 * ct + 4 * q + i;
                out[((size_t)b * NC + c) * NN + m] = acc[ct][mt][i] * linv;
            }
        }
    }
}

extern "C" void kernel_launch(void* const* d_in, const int* in_sizes, int n_in,
                              void* d_out, int out_size, void* d_ws, size_t ws_size,
                              hipStream_t stream) {
    const float* x  = (const float*)d_in[0];
    const float* wq = (const float*)d_in[1];
    const float* bq = (const float*)d_in[2];
    const float* wk = (const float*)d_in[3];
    const float* bk = (const float*)d_in[4];
    const float* wv = (const float*)d_in[5];
    const float* bv = (const float*)d_in[6];
    float* out = (float*)d_out;

    bf16_t* ft  = (bf16_t*)d_ws;                     // [B][N][32]
    bf16_t* gt  = ft + (size_t)NB * NN * NC8;        // [B][N][32]
    bf16_t* hb  = gt + (size_t)NB * NN * NC8;        // [B][C][N]
    bf16_t* wqb = hb + (size_t)NB * NC * NN;         // [32][256]
    bf16_t* wkb = wqb + (size_t)NC8 * NC;            // [32][256]
    bf16_t* wvb = wkb + (size_t)NC8 * NC;            // [256][256]

    cvt_all<<<80, 256, 0, stream>>>(wq, wk, wv, wqb, wkb, wvb);
    proj_fused<<<NB * (NN / 64), 256, 0, stream>>>(x, wqb, bq, wkb, bk, wvb, bv, ft, gt, hb);
    attn<<<NB * (NN / 64), 256, 0, stream>>>(ft, gt, hb, out);
}

// Round 6
// 191.773 us; speedup vs baseline: 1.6772x; 1.6772x over previous
//
#include <hip/hip_runtime.h>
#include <hip/hip_bf16.h>

typedef __bf16 bf16_t;
typedef __bf16 bf16x8 __attribute__((ext_vector_type(8)));
typedef __bf16 bf16x4 __attribute__((ext_vector_type(4)));
typedef float  f32x4  __attribute__((ext_vector_type(4)));

#define NB  8
#define NC  256
#define NC8 32
#define NN  4096
#define XS  264   // xs row stride in proj_fused (528B = 33*16, b128-aligned)

#define MFMA16(a, b, c) __builtin_amdgcn_mfma_f32_16x16x32_bf16((a), (b), (c), 0, 0, 0)

// ---------------------------------------------------------------------------
// Kernel 0: fp32 -> bf16 for all three weight matrices in one launch.
// ---------------------------------------------------------------------------
__global__ __launch_bounds__(256) void cvt_all(const float* __restrict__ wq,
                                               const float* __restrict__ wk,
                                               const float* __restrict__ wv,
                                               bf16_t* __restrict__ wqb,
                                               bf16_t* __restrict__ wkb,
                                               bf16_t* __restrict__ wvb) {
    int i = blockIdx.x * 256 + threadIdx.x;   // 0..20479
    const float* src; bf16_t* dst; int off;
    if (i < 2048)      { src = wq; dst = wqb; off = i; }
    else if (i < 4096) { src = wk; dst = wkb; off = i - 2048; }
    else               { src = wv; dst = wvb; off = i - 4096; }
    float4 v = reinterpret_cast<const float4*>(src)[off];
    bf16x4 o;
    o[0] = (bf16_t)v.x; o[1] = (bf16_t)v.y; o[2] = (bf16_t)v.z; o[3] = (bf16_t)v.w;
    reinterpret_cast<bf16x4*>(dst)[off] = o;
}

// ---------------------------------------------------------------------------
// Kernel 1: FUSED transpose + q/k/v projections per (b, n-tile of 64).
// h is now written in A-fragment-friendly tiled layout:
//   h32[b][n/32][c][n%32]   (each [c][32n] panel = 1KB contiguous per 16 c)
// so attn's O-phase h-loads are fully contiguous 1KB wave reads instead of
// 16-cacheline scatters (stride-8KB lanes). Everything else unchanged.
// ---------------------------------------------------------------------------
__global__ __launch_bounds__(256) void proj_fused(const float* __restrict__ x,
                                                  const bf16_t* __restrict__ wq,
                                                  const float* __restrict__ bq,
                                                  const bf16_t* __restrict__ wk,
                                                  const float* __restrict__ bk,
                                                  const bf16_t* __restrict__ wv,
                                                  const float* __restrict__ bv,
                                                  bf16_t* __restrict__ ft,
                                                  bf16_t* __restrict__ gt,
                                                  bf16_t* __restrict__ h) {
    __shared__ bf16_t tile[64][72];
    __shared__ bf16_t xs[64 * XS];      // [n_loc][c]

    const int bx = blockIdx.x;          // 512
    const int b  = bx >> 6;
    const int n0 = (bx & 63) * 64;
    const int t  = threadIdx.x;
    const int w    = t >> 6;
    const int lane = t & 63;
    const int q    = lane >> 4;
    const int r    = lane & 15;

    const int cl  = t >> 4;
    const int nl  = (t & 15) * 4;
    const int nb_ = t >> 3;
    const int cl2 = (t & 7) * 8;

    // ---- hoisted x loads: all 16 in flight at once
    float4 xv[16];
#pragma unroll
    for (int cp = 0; cp < 4; ++cp)
#pragma unroll
        for (int p = 0; p < 4; ++p)
            xv[4 * cp + p] = *reinterpret_cast<const float4*>(
                x + ((size_t)b * NC + 64 * cp + cl + 16 * p) * NN + n0 + nl);

    for (int cp = 0; cp < 4; ++cp) {
#pragma unroll
        for (int p = 0; p < 4; ++p) {
            const int cc = cl + 16 * p;
            float4 v = xv[4 * cp + p];
            bf16x4 bv4;
            bv4[0] = (bf16_t)v.x; bv4[1] = (bf16_t)v.y; bv4[2] = (bf16_t)v.z; bv4[3] = (bf16_t)v.w;
            *reinterpret_cast<bf16x4*>(&tile[cc][nl]) = bv4;
        }
        __syncthreads();
#pragma unroll
        for (int p = 0; p < 2; ++p) {
            const int nn = nb_ + 32 * p;
            bf16x8 v;
            for (int i = 0; i < 8; ++i) v[i] = tile[cl2 + i][nn];
            *reinterpret_cast<bf16x8*>(&xs[nn * XS + 64 * cp + cl2]) = v;
        }
        __syncthreads();
    }

    // ---- q/k projections (weight + activation prefetch, depth 1)
    {
        const bf16_t* xrow = &xs[(16 * w + r) * XS];
        f32x4 accq[2], acck[2];
        for (int ot = 0; ot < 2; ++ot) {
            accq[ot] = (f32x4){0.f, 0.f, 0.f, 0.f};
            acck[ot] = (f32x4){0.f, 0.f, 0.f, 0.f};
        }
        bf16x8 a_c  = *reinterpret_cast<const bf16x8*>(xrow + 8 * q);
        bf16x8 fq_c[2], fk_c[2];
#pragma unroll
        for (int ot = 0; ot < 2; ++ot) {
            fq_c[ot] = *reinterpret_cast<const bf16x8*>(wq + (size_t)(16 * ot + r) * NC + 8 * q);
            fk_c[ot] = *reinterpret_cast<const bf16x8*>(wk + (size_t)(16 * ot + r) * NC + 8 * q);
        }
        for (int k0 = 0; k0 < NC; k0 += 32) {
            const int kn = (k0 + 32 < NC) ? k0 + 32 : 0;
            bf16x8 a_n = *reinterpret_cast<const bf16x8*>(xrow + kn + 8 * q);
            bf16x8 fq_n[2], fk_n[2];
#pragma unroll
            for (int ot = 0; ot < 2; ++ot) {
                fq_n[ot] = *reinterpret_cast<const bf16x8*>(wq + (size_t)(16 * ot + r) * NC + kn + 8 * q);
                fk_n[ot] = *reinterpret_cast<const bf16x8*>(wk + (size_t)(16 * ot + r) * NC + kn + 8 * q);
            }
#pragma unroll
            for (int ot = 0; ot < 2; ++ot) {
                accq[ot] = MFMA16(a_c, fq_c[ot], accq[ot]);
                acck[ot] = MFMA16(a_c, fk_c[ot], acck[ot]);
            }
            a_c = a_n;
#pragma unroll
            for (int ot = 0; ot < 2; ++ot) { fq_c[ot] = fq_n[ot]; fk_c[ot] = fk_n[ot]; }
        }
        for (int ot = 0; ot < 2; ++ot) {
            const int o = 16 * ot + r;
            const float biq = bq[o];
            const float bik = bk[o];
            for (int i = 0; i < 4; ++i) {
                const int n = n0 + 16 * w + 4 * q + i;
                ft[((size_t)b * NN + n) * NC8 + o] = (bf16_t)(accq[ot][i] + biq);
                gt[((size_t)b * NN + n) * NC8 + o] = (bf16_t)(acck[ot][i] + bik);
            }
        }
    }

    // ---- v projection (wv prefetch, depth 1)
    f32x4 vacc[4][4];
    for (int ct = 0; ct < 4; ++ct)
        for (int nt = 0; nt < 4; ++nt) vacc[ct][nt] = (f32x4){0.f, 0.f, 0.f, 0.f};

    bf16x8 wv_c[4];
#pragma unroll
    for (int ct = 0; ct < 4; ++ct)
        wv_c[ct] = *reinterpret_cast<const bf16x8*>(
            wv + (size_t)(64 * ct + 16 * w + r) * NC + 8 * q);

    for (int k0 = 0; k0 < NC; k0 += 32) {
        const int kn = (k0 + 32 < NC) ? k0 + 32 : 0;
        bf16x8 wv_n[4];
#pragma unroll
        for (int ct = 0; ct < 4; ++ct)
            wv_n[ct] = *reinterpret_cast<const bf16x8*>(
                wv + (size_t)(64 * ct + 16 * w + r) * NC + kn + 8 * q);
        bf16x8 bfr[4];
#pragma unroll
        for (int nt = 0; nt < 4; ++nt)
            bfr[nt] = *reinterpret_cast<const bf16x8*>(&xs[(16 * nt + r) * XS + k0 + 8 * q]);
#pragma unroll
        for (int ct = 0; ct < 4; ++ct)
#pragma unroll
            for (int nt = 0; nt < 4; ++nt)
                vacc[ct][nt] = MFMA16(wv_c[ct], bfr[nt], vacc[ct][nt]);
#pragma unroll
        for (int ct = 0; ct < 4; ++ct) wv_c[ct] = wv_n[ct];
    }
    // ---- h epilogue: tiled layout h32[b][n/32][c][n%32]
    for (int ct = 0; ct < 4; ++ct) {
        for (int nt = 0; nt < 4; ++nt) {
            const int n32 = (n0 >> 5) + (nt >> 1);          // global n/32 chunk
            const int dn  = 16 * (nt & 1) + r;              // n%32
            for (int i = 0; i < 4; ++i) {
                const int c = 64 * ct + 16 * w + 4 * q + i;
                h[(((size_t)b * 128 + n32) * NC + c) * 32 + dn] = (bf16_t)(vacc[ct][nt][i] + bv[c]);
            }
        }
    }
}

// ---------------------------------------------------------------------------
// Kernel 2: attention, 8 waves / BN=128 (R4 structure, non-draining barrier).
// ONLY change vs R4: h reads use the tiled h32[b][n/32][c][n%32] layout, so
// each O_STEP h-load is a fully contiguous 1KB wave read (lane = crow*64B +
// q*16B within one [c-tile][32n] panel) instead of a 16-cacheline scatter.
// ---------------------------------------------------------------------------
#define O_STEP(HU, HL, KC, LOFF)                                               \
    {                                                                          \
        _Pragma("unroll")                                                      \
        for (int ct = 0; ct < 2; ++ct)                                         \
            HL[ct] = *reinterpret_cast<const bf16x8*>(                         \
                hrow[ct] + (size_t)(LOFF) * 256);                              \
        bf16x8 pf[4];                                                          \
        _Pragma("unroll")                                                      \
        for (int mt = 0; mt < 4; ++mt) {                                       \
            const int row = 16 * mt + r;                                       \
            pf[mt] = *reinterpret_cast<const bf16x8*>(                         \
                &Pb[(row << 7) + (((4 * (KC) + q) ^ rq) << 3)]);               \
        }                                                                      \
        _Pragma("unroll")                                                      \
        for (int ct = 0; ct < 2; ++ct)                                         \
            _Pragma("unroll")                                                  \
            for (int mt = 0; mt < 4; ++mt)                                     \
                acc[ct][mt] = MFMA16(HU[ct], pf[mt], acc[ct][mt]);             \
    }

__global__ __launch_bounds__(512, 4) void attn(const bf16_t* __restrict__ ft,
                                               const bf16_t* __restrict__ gt,
                                               const bf16_t* __restrict__ h,
                                               float* __restrict__ out) {
    __shared__ bf16_t P[2 * 64 * 128];   // 32 KB, double buffered
    __shared__ float  l_lds[64];

    const int bx = blockIdx.x;       // 512
    const int b  = bx & 7;           // XCD pin
    const int m0 = (bx >> 3) * 64;
    const int tid  = threadIdx.x;
    const int w    = tid >> 6;       // 0..7
    const int lane = tid & 63;
    const int q    = lane >> 4;
    const int r    = lane & 15;
    const int rq   = r & 7;

    if (tid < 64) l_lds[tid] = 0.f;

    bf16x8 qf[4];
#pragma unroll
    for (int mt = 0; mt < 4; ++mt)
        qf[mt] = *reinterpret_cast<const bf16x8*>(
            gt + ((size_t)b * NN + m0 + 16 * mt + r) * NC8 + 8 * q);

    f32x4 acc[2][4];
#pragma unroll
    for (int ct = 0; ct < 2; ++ct)
#pragma unroll
        for (int mt = 0; mt < 4; ++mt) acc[ct][mt] = (f32x4){0.f, 0.f, 0.f, 0.f};
    float lp[4] = {0.f, 0.f, 0.f, 0.f};

    const bf16_t* fb = ft + (size_t)b * NN * NC8;
    const bf16_t* hb = h + (size_t)b * 128 * NC * 32;   // h32[b]...
    const f32x4 zero = (f32x4){0.f, 0.f, 0.f, 0.f};

    // h32 A-fragment base: c-row = 32w+16ct+r, within-panel offset 8q.
    // Panel for n-offset LOFF (multiple of 32) is at + LOFF*256 elements.
    const bf16_t* hrow[2];
#pragma unroll
    for (int ct = 0; ct < 2; ++ct)
        hrow[ct] = hb + (size_t)(32 * w + 16 * ct + r) * 32 + 8 * q;
    // ft fragment base for wave rows [16w, 16w+16): row = 16w + r
    const bf16_t* fptr = fb + (size_t)(16 * w + r) * NC8 + 8 * q;

    // ---- prologue: s(chunk 0); h0 = chunk0/kc0
    f32x4 s[4];
    {
        bf16x8 a0 = *reinterpret_cast<const bf16x8*>(fptr);
#pragma unroll
        for (int mt = 0; mt < 4; ++mt) s[mt] = MFMA16(a0, qf[mt], zero);
    }
    bf16x8 h0[2], h1[2];
#pragma unroll
    for (int ct = 0; ct < 2; ++ct)
        h0[ct] = *reinterpret_cast<const bf16x8*>(hrow[ct]);

    for (int ii = 0; ii < 32; ++ii) {
        bf16_t* Pb = &P[(ii & 1) << 13];
        const int nb = ii * 128;
        const int nld = (ii + 1 < 32 ? ii + 1 : 31) * 128;

        // ---- issue af load for chunk ii+1 FIRST (max slack, crosses barrier)
        bf16x8 af0 = *reinterpret_cast<const bf16x8*>(fptr + (size_t)nld * NC8);

        // ---- exp + write P[cur] (64m x 128n, swizzled); wave w owns n-cols [16w,16w+16)
#pragma unroll
        for (int mt = 0; mt < 4; ++mt) {
            float e0 = __expf(s[mt][0]);
            float e1 = __expf(s[mt][1]);
            float e2 = __expf(s[mt][2]);
            float e3 = __expf(s[mt][3]);
            lp[mt] += (e0 + e1) + (e2 + e3);
            bf16x4 pv;
            pv[0] = (bf16_t)e0; pv[1] = (bf16_t)e1; pv[2] = (bf16_t)e2; pv[3] = (bf16_t)e3;
            const int row  = 16 * mt + r;
            const int nblk = 2 * w + (q >> 1);
            *reinterpret_cast<bf16x4*>(
                &Pb[(row << 7) + ((nblk ^ rq) << 3) + 4 * (q & 1)]) = pv;
        }

        // ---- NON-DRAINING barrier: order LDS only; VMEM prefetch survives
        asm volatile("s_waitcnt lgkmcnt(0)" ::: "memory");
        __builtin_amdgcn_sched_barrier(0);
        __builtin_amdgcn_s_barrier();
        __builtin_amdgcn_sched_barrier(0);

        // ---- O phase: 4 k-chunks of 32 n, h ping-pong one chunk ahead
        const int nbn = (ii + 1 < 32 ? nb + 128 : nb);   // next iter kc0 (clamped)
        __builtin_amdgcn_s_setprio(1);
        O_STEP(h0, h1, 0, nb + 32);
        O_STEP(h1, h0, 1, nb + 64);
        O_STEP(h0, h1, 2, nb + 96);
        O_STEP(h1, h0, 3, nbn);

        // ---- S(ii+1)
#pragma unroll
        for (int mt = 0; mt < 4; ++mt) s[mt] = MFMA16(af0, qf[mt], zero);
        __builtin_amdgcn_s_setprio(0);
    }

    // ---- reduce l partials (cold path: full syncs are fine here)
    __syncthreads();
#pragma unroll
    for (int mt = 0; mt < 4; ++mt) {
        float v = lp[mt];
        v += __shfl_xor(v, 16);
        v += __shfl_xor(v, 32);
        if (q == 0) atomicAdd(&l_lds[16 * mt + r], v);
    }
    __syncthreads();

    // ---- epilogue: out[b][c][m] = acc / l[m]
#pragma unroll
    for (int ct = 0; ct < 2; ++ct) {
#pragma unroll
        for (int mt = 0; mt < 4; ++mt) {
            const int m = m0 + 16 * mt + r;
            const float linv = 1.0f / l_lds[16 * mt + r];
#pragma unroll
            for (int i = 0; i < 4; ++i) {
                const int c = 32 * w + 16 * ct + 4 * q + i;
                out[((size_t)b * NC + c) * NN + m] = acc[ct][mt][i] * linv;
            }
        }
    }
}

extern "C" void kernel_launch(void* const* d_in, const int* in_sizes, int n_in,
                              void* d_out, int out_size, void* d_ws, size_t ws_size,
                              hipStream_t stream) {
    const float* x  = (const float*)d_in[0];
    const float* wq = (const float*)d_in[1];
    const float* bq = (const float*)d_in[2];
    const float* wk = (const float*)d_in[3];
    const float* bk = (const float*)d_in[4];
    const float* wv = (const float*)d_in[5];
    const float* bv = (const float*)d_in[6];
    float* out = (float*)d_out;

    bf16_t* ft  = (bf16_t*)d_ws;                     // [B][N][32]
    bf16_t* gt  = ft + (size_t)NB * NN * NC8;        // [B][N][32]
    bf16_t* hb  = gt + (size_t)NB * NN * NC8;        // h32: [B][N/32][C][32]
    bf16_t* wqb = hb + (size_t)NB * NC * NN;         // [32][256]
    bf16_t* wkb = wqb + (size_t)NC8 * NC;            // [32][256]
    bf16_t* wvb = wkb + (size_t)NC8 * NC;            // [256][256]

    cvt_all<<<80, 256, 0, stream>>>(wq, wk, wv, wqb, wkb, wvb);
    proj_fused<<<NB * (NN / 64), 256, 0, stream>>>(x, wqb, bq, wkb, bk, wvb, bv, ft, gt, hb);
    attn<<<NB * (NN / 64), 512, 0, stream>>>(ft, gt, hb, out);
}